// Round 1
// baseline (84.673 us; speedup 1.0000x reference)
//
#include <hip/hip_runtime.h>

// Kendall tau: tau = sum_{i<j} tanh((p_i-p_j)(t_i-t_j)/T) / (n(n-1)/2), T=0.1.
// tanh(10d) = 1 - 2/(exp2(d*C)+1), C = 20/ln(2); exp2 saturation gives exact
// +-1 tails, and the i==j self-pair gives rcp(2.0)=0.5 -> term exactly 0.
//
// Triangular tiling: 64 tiles x 128 elems -> 2080 block-pairs (a<=b).
//  a<b : full 128x128 cross, each unordered pair once (weight 1)
//  a==b: full ordered cross incl self (self terms exactly 0), weight 1/2
// Per thread: 1 i in regs, 64 j's from LDS in float4 chunks, 8 acc chains.
//
// STRUCTURAL CHANGE THIS ROUND (theory: timed window is dominated by fixed
// machinery, not arithmetic — halving the pair count last session moved dur
// by ~0):
//  * NO workspace usage at all. Probes whether the 39.5us 256MiB ws-poison
//    fill (top-5 dispatches in rocprof, 85% of HBM peak) is conditional on
//    ws use inside the timed bracket.
//  * Single kernel node: per-block contribution goes straight into d_out via
//    native f32 atomic add (unsafeAtomicAdd -> global_atomic_add_f32,
//    device scope). 2080 atomics arrive staggered by block completion, so
//    serialization at L2 hides under compute. d_out is zeroed by a 4-byte
//    memset node (capturable; not on the graph-capture ban list).
//  * Math is bit-identical per term; only the cross-block summation order
//    changes (atomic order), expected absmax ~1e-6.

#define NTOT 8192
#define TILE 128
#define NT   (NTOT / TILE)           // 64
#define NBLK (NT * (NT + 1) / 2)     // 2080
#define TPB  256

__device__ __forceinline__ int rowoff(int a) {
    return a * NT - (a * (a - 1)) / 2;   // blocks before row a of the triangle
}

__global__ __launch_bounds__(TPB) void ktau_tri(const float* __restrict__ pred,
                                                const float* __restrict__ targ,
                                                float* __restrict__ out) {
    const float C = 28.853900817779268f;   // 2*10*log2(e)
    const int tid = threadIdx.x;
    const int bid = blockIdx.x;

    // Decode bid -> (a,b), a<=b (scalar, uniform).
    int a = (int)((2.0 * NT + 1.0 -
                   sqrt((2.0 * NT + 1.0) * (2.0 * NT + 1.0) - 8.0 * (double)bid)) * 0.5);
    while (rowoff(a + 1) <= bid) ++a;
    while (a > 0 && rowoff(a) > bid) --a;
    const int b = a + (bid - rowoff(a));

    // B-tile (j side) -> LDS, C folded into t.
    __shared__ float sjp[TILE];
    __shared__ float sjt[TILE];
    if (tid < TILE) {
        sjp[tid] = pred[b * TILE + tid];
        sjt[tid] = targ[b * TILE + tid] * C;
    }

    // A-tile (i side): one i per lane-slot; two j-halves across the block.
    const int il = tid & (TILE - 1);
    const int jh = tid >> 7;               // 0 or 1: which 64-wide j half
    const float pi = pred[a * TILE + il];
    const float ti = targ[a * TILE + il] * C;
    __syncthreads();

    float acc[8];
#pragma unroll
    for (int jj = 0; jj < 8; ++jj) acc[jj] = 0.0f;

    const float4* sp4 = (const float4*)sjp;
    const float4* st4 = (const float4*)sjt;

#pragma unroll
    for (int jc = 0; jc < 8; ++jc) {       // 8 chunks of 8 j's in this half
        const int q = jh * 16 + jc * 2;    // float4 index (wave-uniform -> LDS broadcast)
        const float4 pj0 = sp4[q],     pj1 = sp4[q + 1];
        const float4 tj0 = st4[q],     tj1 = st4[q + 1];
        const float pj[8] = {pj0.x, pj0.y, pj0.z, pj0.w, pj1.x, pj1.y, pj1.z, pj1.w};
        const float tj[8] = {tj0.x, tj0.y, tj0.z, tj0.w, tj1.x, tj1.y, tj1.z, tj1.w};
#pragma unroll
        for (int jj = 0; jj < 8; ++jj) {   // 8 independent chains
            const float x = (pi - pj[jj]) * (ti - tj[jj]);
            const float e = __builtin_amdgcn_exp2f(x);        // saturates to inf/0 at tails
            const float r = __builtin_amdgcn_rcpf(e + 1.0f);  // rcp(inf)=0, rcp(2)=0.5 exact
            acc[jj] = __builtin_fmaf(-2.0f, r, acc[jj]);      // term = 1 - 2r; +1 counted later
        }
    }

    float fsum = 0.0f;
#pragma unroll
    for (int jj = 0; jj < 8; ++jj) fsum += acc[jj];

    double dacc = (double)fsum;
#pragma unroll
    for (int off = 32; off > 0; off >>= 1)
        dacc += __shfl_down(dacc, off, 64);

    __shared__ double red[TPB / 64];
    if ((tid & 63) == 0) red[tid >> 6] = dacc;
    __syncthreads();
    if (tid == 0) {
        double s = 0.0;
#pragma unroll
        for (int w = 0; w < TPB / 64; ++w) s += red[w];
        s += (double)(TPB * 64);           // the "+1" of each of the 16384 terms, exact
        if (a == b) s *= 0.5;              // diagonal counted twice -> exact halving
        const double n_pairs = (double)NTOT * (double)(NTOT - 1) * 0.5;  // 33550336
        // Native device-scope f32 atomic add (global_atomic_add_f32). One per
        // block; arrival is staggered by block completion so L2 serialization
        // hides under remaining compute.
        unsafeAtomicAdd(out, (float)(s / n_pairs));
    }
}

extern "C" void kernel_launch(void* const* d_in, const int* in_sizes, int n_in,
                              void* d_out, int out_size, void* d_ws, size_t ws_size,
                              hipStream_t stream) {
    const float* pred = (const float*)d_in[0];
    const float* targ = (const float*)d_in[1];
    float* out = (float*)d_out;
    (void)d_ws; (void)ws_size;             // deliberately workspace-free this round

    hipMemsetAsync(out, 0, sizeof(float), stream);   // 4-byte memset node
    ktau_tri<<<NBLK, TPB, 0, stream>>>(pred, targ, out);
}

// Round 3
// 68.495 us; speedup vs baseline: 1.2362x; 1.2362x over previous
//
#include <hip/hip_runtime.h>

// Kendall tau: tau = sum_{i<j} tanh((p_i-p_j)(t_i-t_j)/T) / (n(n-1)/2), T=0.1.
// tanh(10d) = 1 - 2/(exp2(d*C)+1), C = 20/ln(2); exp2 saturation gives exact
// +-1 tails, and the i==j self-pair gives rcp(2.0)=0.5 -> term exactly 0.
//
// Triangular tiling: 64 tiles x 128 elems -> 2080 block-pairs (a<=b).
//  a<b : full 128x128 cross, each unordered pair once (weight 1)
//  a==b: full ordered cross incl self (self terms exactly 0), weight 1/2
//
// ROUND-2 STRUCTURE (resubmitted after broker timeout; no result last round):
//  * Round 1 proved the 256MiB ws-poison fill (39.4us) is UNCONDITIONAL and
//    that 2080 same-address f32 atomics serialize into a ~17us tail
//    (~9ns/atomic at the coherence point). Reverted to partial[] + final
//    kernel -- the round-0 structure that measured 67.7us.
//  * Scheduling fix: residency capacity is exactly 2048 blocks
//    (256 CUs x 8 blocks/CU at 256 thr, low VGPR). Round 0's 2080 blocks
//    left a 32-block straggler round (~+2-3us: a lone block is as long as
//    the whole trans-pipe-bound kernel). Grid is now 2048; blocks 0..31
//    grid-stride to a second tile-pair, so those CUs carry +12.5% work
//    concurrently instead of a serial tail.
//  * Per-term math bit-identical; +1-count and diagonal 1/2-weight applied
//    per pair in double (no new f32 cancellation).

#define NTOT  8192
#define TILE  128
#define NT    (NTOT / TILE)            // 64
#define NPAIR (NT * (NT + 1) / 2)      // 2080
#define GRID  2048                     // exact residency: one scheduling round
#define TPB   256

__device__ __forceinline__ int rowoff(int a) {
    return a * NT - (a * (a - 1)) / 2;   // blocks before row a of the triangle
}

__global__ __launch_bounds__(TPB) void ktau_tri(const float* __restrict__ pred,
                                                const float* __restrict__ targ,
                                                double* __restrict__ partial) {
    const float C = 28.853900817779268f;   // 2*10*log2(e)
    const int tid = threadIdx.x;

    __shared__ float sjp[TILE];
    __shared__ float sjt[TILE];
    __shared__ double red[TPB / 64];

    const int il = tid & (TILE - 1);
    const int jh = tid >> 7;               // 0 or 1: which 64-wide j half

    double dacc = 0.0;

    for (int p = blockIdx.x; p < NPAIR; p += GRID) {   // 1 pair/block, 2 for bid<32
        // Decode p -> (a,b), a<=b (scalar, uniform).
        int a = (int)((2.0 * NT + 1.0 -
                       sqrt((2.0 * NT + 1.0) * (2.0 * NT + 1.0) - 8.0 * (double)p)) * 0.5);
        while (rowoff(a + 1) <= p) ++a;
        while (a > 0 && rowoff(a) > p) --a;
        const int b = a + (p - rowoff(a));

        __syncthreads();                   // prior-iter LDS reads complete
        if (tid < TILE) {
            sjp[tid] = pred[b * TILE + tid];
            sjt[tid] = targ[b * TILE + tid] * C;
        }
        const float pi = pred[a * TILE + il];
        const float ti = targ[a * TILE + il] * C;
        __syncthreads();

        float acc[8];
#pragma unroll
        for (int jj = 0; jj < 8; ++jj) acc[jj] = 0.0f;

        const float4* sp4 = (const float4*)sjp;
        const float4* st4 = (const float4*)sjt;

#pragma unroll
        for (int jc = 0; jc < 8; ++jc) {   // 8 chunks of 8 j's in this half
            const int q = jh * 16 + jc * 2;  // float4 idx (wave-uniform -> LDS broadcast)
            const float4 pj0 = sp4[q],     pj1 = sp4[q + 1];
            const float4 tj0 = st4[q],     tj1 = st4[q + 1];
            const float pj[8] = {pj0.x, pj0.y, pj0.z, pj0.w, pj1.x, pj1.y, pj1.z, pj1.w};
            const float tj[8] = {tj0.x, tj0.y, tj0.z, tj0.w, tj1.x, tj1.y, tj1.z, tj1.w};
#pragma unroll
            for (int jj = 0; jj < 8; ++jj) {   // 8 independent chains
                const float x = (pi - pj[jj]) * (ti - tj[jj]);
                const float e = __builtin_amdgcn_exp2f(x);        // saturates at tails
                const float r = __builtin_amdgcn_rcpf(e + 1.0f);  // rcp(inf)=0, rcp(2)=0.5
                acc[jj] = __builtin_fmaf(-2.0f, r, acc[jj]);      // term = 1 - 2r
            }
        }

        float fsum = 0.0f;
#pragma unroll
        for (int jj = 0; jj < 8; ++jj) fsum += acc[jj];

        // +1 per term (64 terms/thread) in double; diagonal tile counted as
        // full ordered cross -> exact halving.
        const double s = (double)fsum + 64.0;
        dacc += (a == b) ? 0.5 * s : s;
    }

    // Block reduction in double.
#pragma unroll
    for (int off = 32; off > 0; off >>= 1)
        dacc += __shfl_down(dacc, off, 64);
    if ((tid & 63) == 0) red[tid >> 6] = dacc;
    __syncthreads();
    if (tid == 0) {
        double s = 0.0;
#pragma unroll
        for (int w = 0; w < TPB / 64; ++w) s += red[w];
        partial[blockIdx.x] = s;
    }
}

__global__ __launch_bounds__(256) void ktau_final(const double* __restrict__ partial,
                                                  float* __restrict__ out) {
    const int tid = threadIdx.x;
    double s = 0.0;
    for (int t = tid; t < GRID; t += 256) s += partial[t];
#pragma unroll
    for (int off = 32; off > 0; off >>= 1)
        s += __shfl_down(s, off, 64);
    __shared__ double red[4];
    if ((tid & 63) == 0) red[tid >> 6] = s;
    __syncthreads();
    if (tid == 0) {
        const double n_pairs = (double)NTOT * (double)(NTOT - 1) * 0.5;  // 33550336
        out[0] = (float)((red[0] + red[1] + red[2] + red[3]) / n_pairs);
    }
}

extern "C" void kernel_launch(void* const* d_in, const int* in_sizes, int n_in,
                              void* d_out, int out_size, void* d_ws, size_t ws_size,
                              hipStream_t stream) {
    const float* pred = (const float*)d_in[0];
    const float* targ = (const float*)d_in[1];
    float* out = (float*)d_out;
    double* partial = (double*)d_ws;   // GRID doubles = 16 KB

    ktau_tri<<<GRID, TPB, 0, stream>>>(pred, targ, partial);
    ktau_final<<<1, 256, 0, stream>>>(partial, out);
}